// Round 5
// baseline (45.727 us; speedup 1.0000x reference)
//
#include <hip/hip_runtime.h>
#include <math.h>

#define NROWS 8192
#define NCOLS 4096
#define RPC 32                     // rows per chunk
#define NCHUNK (NROWS / RPC)       // 256
#define TPB 256
#define CPT 4                      // cols per thread (float4)
#define CTILE (TPB * CPT)          // 1024
#define NTILE (NCOLS / CTILE)      // 4
#define FTPB 128                   // finalize threads per block
#define FBLK (NCOLS / FTPB)        // 32 finalize blocks

typedef float f32x4 __attribute__((ext_vector_type(4)));

// Stage 1: per-(chunk, column) partial tss and colsum, f32 in-loop.
// Branch-free: prefetch row offset clamps to last valid row (wave-uniform
// s_min); da_sh is 0 past the last diff index, and at the clamp cur==nxt so
// the tail contributes exactly 0 through the same arithmetic path.
__global__ __launch_bounds__(TPB) void tss_partial_kernel(
    const float* __restrict__ x,
    float* __restrict__ ptss,
    float* __restrict__ pcs)
{
    const int tid   = threadIdx.x;
    const int tile  = blockIdx.x;   // 0..NTILE-1
    const int chunk = blockIdx.y;   // 0..NCHUNK-1
    const int col   = tile * CTILE + tid * CPT;
    const int r0    = chunk * RPC;

    __shared__ float x0[RPC + 1];
    __shared__ float da_sh[RPC];

    // column-0 values for rows r0..r0+RPC (tiny, L2/L3-shared across tiles)
    if (tid <= RPC) {
        int r = min(r0 + tid, NROWS - 1);
        x0[tid] = x[(size_t)r * NCOLS];
    }
    __syncthreads();
    if (tid < RPC) {
        da_sh[tid] = (r0 + tid + 1 < NROWS) ? (x0[tid + 1] - x0[tid]) : 0.0f;
    }
    __syncthreads();

    const f32x4* row = (const f32x4*)(x + (size_t)r0 * NCOLS + col);
    const int rs = NCOLS / 4;             // row stride in f32x4
    const int maxoff = NROWS - 1 - r0;    // wave-uniform clamp (>= RPC-1)

    float tss0 = 0.f, tss1 = 0.f, tss2 = 0.f, tss3 = 0.f;
    float cs0 = 0.f, cs1 = 0.f, cs2 = 0.f, cs3 = 0.f;

    // depth-3 register pipeline: rA=row[i], rB=row[i+1], rC=row[i+2]
    f32x4 rA = row[0];
    f32x4 rB = row[rs];                   // r0+1 always valid
    f32x4 rC = row[min(2, maxoff) * rs];

    #pragma unroll 4
    for (int i = 0; i < RPC; ++i) {
        const int offc = (i + 3 <= RPC + 2) ? (i + 3) : (RPC + 2);
        const int off  = min(offc, maxoff);
        f32x4 pf = row[off * rs];

        // colsum contribution of row r0+i
        cs0 += rA.x; cs1 += rA.y; cs2 += rA.z; cs3 += rA.w;

        const float da = da_sh[i];
        float db, df;
        db = rB.x - rA.x; df = da - db;
        tss0 += (da * db >= 0.f) ? df : fabsf(df);
        db = rB.y - rA.y; df = da - db;
        tss1 += (da * db >= 0.f) ? df : fabsf(df);
        db = rB.z - rA.z; df = da - db;
        tss2 += (da * db >= 0.f) ? df : fabsf(df);
        db = rB.w - rA.w; df = da - db;
        tss3 += (da * db >= 0.f) ? df : fabsf(df);

        rA = rB;
        rB = rC;
        rC = pf;
    }

    float* pt = ptss + (size_t)chunk * NCOLS + col;
    float* pc = pcs  + (size_t)chunk * NCOLS + col;
    pt[0] = tss0; pt[1] = tss1; pt[2] = tss2; pt[3] = tss3;
    pc[0] = cs0;  pc[1] = cs1;  pc[2] = cs2;  pc[3] = cs3;
}

// Stage 2: per-column chunk-reduce (f64) + score/tan + per-block (t, t*cs) sums.
__global__ __launch_bounds__(FTPB) void tss_finalize_kernel(
    const float* __restrict__ ptss,
    const float* __restrict__ pcs,
    const float* __restrict__ variance,
    double* __restrict__ blk)     // [FBLK][2]
{
    const int tid = threadIdx.x;
    const int j = blockIdx.x * FTPB + tid;  // 0..NCOLS-1
    double tss = 0.0, cs = 0.0;
    #pragma unroll 8
    for (int c = 0; c < NCHUNK; ++c) {
        tss += (double)ptss[(size_t)c * NCOLS + j];
        cs  += (double)pcs[(size_t)c * NCOLS + j];
    }
    double t = 0.0, tc = 0.0;
    if (j >= 1) {
        const double var = (double)variance[0];
        const double SQRT_2PI = 2.5066282746310005024;
        const double coef = 1.0 / (SQRT_2PI * var);
        const double score = coef * exp(-(tss * tss) / (2.0 * var * var));
        t  = tan(score);
        tc = t * cs;
    }
    __shared__ double s1[FTPB];
    __shared__ double s2[FTPB];
    s1[tid] = t; s2[tid] = tc;
    __syncthreads();
    for (int s = FTPB / 2; s > 0; s >>= 1) {
        if (tid < s) { s1[tid] += s1[tid + s]; s2[tid] += s2[tid + s]; }
        __syncthreads();
    }
    if (tid == 0) {
        blk[2 * blockIdx.x]     = s1[0];
        blk[2 * blockIdx.x + 1] = s2[0];
    }
}

// Stage 3: reduce FBLK pairs in one wave.
__global__ __launch_bounds__(64) void tss_reduce_kernel(
    const double* __restrict__ blk,
    float* __restrict__ out)
{
    const int tid = threadIdx.x;
    double st = 0.0, stc = 0.0;
    if (tid < FBLK) {
        st  = blk[2 * tid];
        stc = blk[2 * tid + 1];
    }
    for (int o = 32; o > 0; o >>= 1) {
        st  += __shfl_down(st, o);
        stc += __shfl_down(stc, o);
    }
    if (tid == 0) out[0] = (float)(stc / st);
}

extern "C" void kernel_launch(void* const* d_in, const int* in_sizes, int n_in,
                              void* d_out, int out_size, void* d_ws, size_t ws_size,
                              hipStream_t stream) {
    const float* x   = (const float*)d_in[0];
    const float* var = (const float*)d_in[1];
    float* out = (float*)d_out;

    float* ptss = (float*)d_ws;                            // NCHUNK*NCOLS f32 (4 MiB)
    float* pcs  = ptss + (size_t)NCHUNK * NCOLS;           // NCHUNK*NCOLS f32 (4 MiB)
    double* blk = (double*)(pcs + (size_t)NCHUNK * NCOLS); // FBLK*2 doubles

    dim3 g1(NTILE, NCHUNK);
    tss_partial_kernel<<<g1, TPB, 0, stream>>>(x, ptss, pcs);
    tss_finalize_kernel<<<FBLK, FTPB, 0, stream>>>(ptss, pcs, var, blk);
    tss_reduce_kernel<<<1, 64, 0, stream>>>(blk, out);
}

// Round 6
// 37.597 us; speedup vs baseline: 1.2162x; 1.2162x over previous
//
#include <hip/hip_runtime.h>
#include <math.h>

#define NROWS 8192
#define NCOLS 4096
#define RPC 64                     // rows per chunk
#define NCHUNK (NROWS / RPC)       // 128
#define TPB 256
#define CPT 4                      // cols per thread (float4)
#define CTILE (TPB * CPT)          // 1024
#define NTILE (NCOLS / CTILE)      // 4
#define F2BLK 64                   // stage-2 blocks (64 cols each, 4 threads/col)
#define CPB2 (NCOLS / F2BLK)       // 64 columns per stage-2 block

typedef float f32x4 __attribute__((ext_vector_type(4)));

// Stage 1: per-(chunk, column) partial tss and colsum, f32 in-loop.
// Branch-free: prefetch row offset clamps to last valid row (wave-uniform
// s_min); da_sh is 0 past the last diff index, and at the clamp cur==nxt so
// the tail contributes exactly 0 through the same arithmetic path.
__global__ __launch_bounds__(TPB) void tss_partial_kernel(
    const float* __restrict__ x,
    float* __restrict__ ptss,
    float* __restrict__ pcs)
{
    const int tid   = threadIdx.x;
    const int tile  = blockIdx.x;   // 0..NTILE-1
    const int chunk = blockIdx.y;   // 0..NCHUNK-1
    const int col   = tile * CTILE + tid * CPT;
    const int r0    = chunk * RPC;

    __shared__ float x0[RPC + 1];
    __shared__ float da_sh[RPC];

    if (tid <= RPC) {
        int r = min(r0 + tid, NROWS - 1);
        x0[tid] = x[(size_t)r * NCOLS];
    }
    __syncthreads();
    if (tid < RPC) {
        da_sh[tid] = (r0 + tid + 1 < NROWS) ? (x0[tid + 1] - x0[tid]) : 0.0f;
    }
    __syncthreads();

    const f32x4* row = (const f32x4*)(x + (size_t)r0 * NCOLS + col);
    const int rs = NCOLS / 4;             // row stride in f32x4
    const int maxoff = NROWS - 1 - r0;    // wave-uniform clamp (>= 63)

    float tss0 = 0.f, tss1 = 0.f, tss2 = 0.f, tss3 = 0.f;
    float cs0 = 0.f, cs1 = 0.f, cs2 = 0.f, cs3 = 0.f;

    f32x4 cur = row[0];                   // row r0
    f32x4 nxt = row[rs];                  // row r0+1 (always exists)

    #pragma unroll 8
    for (int i = 0; i < RPC; ++i) {
        const int offc = (i + 2 <= RPC) ? (i + 2) : RPC;
        const int off  = min(offc, maxoff);
        f32x4 pf = row[off * rs];

        cs0 += cur.x; cs1 += cur.y; cs2 += cur.z; cs3 += cur.w;

        const float da = da_sh[i];
        float db, df;
        db = nxt.x - cur.x; df = da - db;
        tss0 += (da * db >= 0.f) ? df : fabsf(df);
        db = nxt.y - cur.y; df = da - db;
        tss1 += (da * db >= 0.f) ? df : fabsf(df);
        db = nxt.z - cur.z; df = da - db;
        tss2 += (da * db >= 0.f) ? df : fabsf(df);
        db = nxt.w - cur.w; df = da - db;
        tss3 += (da * db >= 0.f) ? df : fabsf(df);

        cur = nxt;
        nxt = pf;
    }

    float* pt = ptss + (size_t)chunk * NCOLS + col;
    float* pc = pcs  + (size_t)chunk * NCOLS + col;
    pt[0] = tss0; pt[1] = tss1; pt[2] = tss2; pt[3] = tss3;
    pc[0] = cs0;  pc[1] = cs1;  pc[2] = cs2;  pc[3] = cs3;
}

// Stage 2: 64 blocks x 256 threads; 4 threads per column, each sums 32 chunks
// (coalesced 256B wave loads), LDS combine, then score/tan and a single-wave
// reduction of the 64 per-column (t, t*cs) pairs to one pair per block.
__global__ __launch_bounds__(256) void tss_finalize_kernel(
    const float* __restrict__ ptss,
    const float* __restrict__ pcs,
    const float* __restrict__ variance,
    double* __restrict__ blk)     // [F2BLK][2]
{
    const int tid  = threadIdx.x;
    const int part = tid >> 6;          // 0..3
    const int cpos = tid & 63;          // 0..63
    const int j    = blockIdx.x * CPB2 + cpos;

    double tss = 0.0, cs = 0.0;
    #pragma unroll 8
    for (int c = part * (NCHUNK / 4); c < (part + 1) * (NCHUNK / 4); ++c) {
        tss += (double)ptss[(size_t)c * NCOLS + j];
        cs  += (double)pcs[(size_t)c * NCOLS + j];
    }

    __shared__ double stss[4][CPB2];
    __shared__ double scs[4][CPB2];
    stss[part][cpos] = tss;
    scs[part][cpos]  = cs;
    __syncthreads();

    if (tid < 64) {
        tss = stss[0][cpos] + stss[1][cpos] + stss[2][cpos] + stss[3][cpos];
        cs  = scs[0][cpos] + scs[1][cpos] + scs[2][cpos] + scs[3][cpos];

        double t = 0.0, tc = 0.0;
        if (j >= 1) {
            const double var = (double)variance[0];
            const double SQRT_2PI = 2.5066282746310005024;
            const double coef = 1.0 / (SQRT_2PI * var);
            const double score = coef * exp(-(tss * tss) / (2.0 * var * var));
            t  = tan(score);
            tc = t * cs;
        }
        // single-wave shuffle reduce over 64 lanes
        for (int o = 32; o > 0; o >>= 1) {
            t  += __shfl_down(t, o);
            tc += __shfl_down(tc, o);
        }
        if (cpos == 0) {
            blk[2 * blockIdx.x]     = t;
            blk[2 * blockIdx.x + 1] = tc;
        }
    }
}

// Stage 3: reduce F2BLK pairs in one wave.
__global__ __launch_bounds__(64) void tss_reduce_kernel(
    const double* __restrict__ blk,
    float* __restrict__ out)
{
    const int tid = threadIdx.x;
    double st  = blk[2 * tid];
    double stc = blk[2 * tid + 1];
    for (int o = 32; o > 0; o >>= 1) {
        st  += __shfl_down(st, o);
        stc += __shfl_down(stc, o);
    }
    if (tid == 0) out[0] = (float)(stc / st);
}

extern "C" void kernel_launch(void* const* d_in, const int* in_sizes, int n_in,
                              void* d_out, int out_size, void* d_ws, size_t ws_size,
                              hipStream_t stream) {
    const float* x   = (const float*)d_in[0];
    const float* var = (const float*)d_in[1];
    float* out = (float*)d_out;

    float* ptss = (float*)d_ws;                            // NCHUNK*NCOLS f32 (2 MiB)
    float* pcs  = ptss + (size_t)NCHUNK * NCOLS;           // NCHUNK*NCOLS f32 (2 MiB)
    double* blk = (double*)(pcs + (size_t)NCHUNK * NCOLS); // F2BLK*2 doubles

    dim3 g1(NTILE, NCHUNK);
    tss_partial_kernel<<<g1, TPB, 0, stream>>>(x, ptss, pcs);
    tss_finalize_kernel<<<F2BLK, 256, 0, stream>>>(ptss, pcs, var, blk);
    tss_reduce_kernel<<<1, 64, 0, stream>>>(blk, out);
}

// Round 7
// 32.540 us; speedup vs baseline: 1.4053x; 1.1554x over previous
//
#include <hip/hip_runtime.h>
#include <math.h>

#define NROWS 8192
#define NCOLS 4096
#define RPC 32                     // rows per chunk
#define NCHUNK (NROWS / RPC)       // 256 -> grid = 256 blocks = 1 per CU
#define TPB 1024                   // 16 waves/block = 4 per SIMD
#define CPT 4                      // cols per thread (float4); 1024*4 = 4096
#define F2BLK 128                  // stage-2 blocks
#define CPB2 (NCOLS / F2BLK)       // 32 columns per stage-2 block
#define PARTS 8                    // stage-2 threads per column

typedef float f32x4 __attribute__((ext_vector_type(4)));

// Stage 1: one block per 32-row slab, full row width. Per-thread 4 columns.
// Branch-free tail: prefetch row offset clamps to last valid row (wave-uniform
// s_min); da_sh[i]=0 past the last diff, and at the clamp cur==nxt, so the
// tail contributes exactly 0 through the same arithmetic path.
__global__ __launch_bounds__(TPB) void tss_partial_kernel(
    const float* __restrict__ x,
    float* __restrict__ ptss,
    float* __restrict__ pcs)
{
    const int tid   = threadIdx.x;
    const int chunk = blockIdx.x;   // 0..NCHUNK-1
    const int col   = tid * CPT;
    const int r0    = chunk * RPC;

    __shared__ float x0[RPC + 1];
    __shared__ float da_sh[RPC];

    if (tid <= RPC) {
        int r = min(r0 + tid, NROWS - 1);
        x0[tid] = x[(size_t)r * NCOLS];
    }
    __syncthreads();
    if (tid < RPC) {
        da_sh[tid] = (r0 + tid + 1 < NROWS) ? (x0[tid + 1] - x0[tid]) : 0.0f;
    }
    __syncthreads();

    const f32x4* row = (const f32x4*)(x + (size_t)r0 * NCOLS + col);
    const int rs = NCOLS / 4;             // row stride in f32x4
    const int maxoff = NROWS - 1 - r0;    // wave-uniform clamp (>= 31)

    float tss0 = 0.f, tss1 = 0.f, tss2 = 0.f, tss3 = 0.f;
    float cs0 = 0.f, cs1 = 0.f, cs2 = 0.f, cs3 = 0.f;

    f32x4 cur = row[0];                          // row r0
    f32x4 nxt = row[min(1, maxoff) * rs];        // row r0+1

    #pragma unroll 8
    for (int i = 0; i < RPC; ++i) {
        const int offc = (i + 2 <= RPC) ? (i + 2) : RPC;
        const int off  = min(offc, maxoff);
        f32x4 pf = row[off * rs];

        cs0 += cur.x; cs1 += cur.y; cs2 += cur.z; cs3 += cur.w;

        const float da = da_sh[i];
        float db, df;
        db = nxt.x - cur.x; df = da - db;
        tss0 += (da * db >= 0.f) ? df : fabsf(df);
        db = nxt.y - cur.y; df = da - db;
        tss1 += (da * db >= 0.f) ? df : fabsf(df);
        db = nxt.z - cur.z; df = da - db;
        tss2 += (da * db >= 0.f) ? df : fabsf(df);
        db = nxt.w - cur.w; df = da - db;
        tss3 += (da * db >= 0.f) ? df : fabsf(df);

        cur = nxt;
        nxt = pf;
    }

    float* pt = ptss + (size_t)chunk * NCOLS + col;
    float* pc = pcs  + (size_t)chunk * NCOLS + col;
    pt[0] = tss0; pt[1] = tss1; pt[2] = tss2; pt[3] = tss3;
    pc[0] = cs0;  pc[1] = cs1;  pc[2] = cs2;  pc[3] = cs3;
}

// Stage 2: 128 blocks x 256 threads; PARTS=8 threads per column, each sums 32
// chunks (coalesced within a wave), LDS combine + tree, per-block (t, t*cs).
__global__ __launch_bounds__(256) void tss_finalize_kernel(
    const float* __restrict__ ptss,
    const float* __restrict__ pcs,
    const float* __restrict__ variance,
    double* __restrict__ blk)     // [F2BLK][2]
{
    const int tid  = threadIdx.x;
    const int part = tid >> 5;          // 0..7
    const int cpos = tid & 31;          // 0..31
    const int j    = blockIdx.x * CPB2 + cpos;

    double tss = 0.0, cs = 0.0;
    #pragma unroll 8
    for (int c = part * (NCHUNK / PARTS); c < (part + 1) * (NCHUNK / PARTS); ++c) {
        tss += (double)ptss[(size_t)c * NCOLS + j];
        cs  += (double)pcs[(size_t)c * NCOLS + j];
    }

    __shared__ double stss[PARTS][CPB2];
    __shared__ double scs[PARTS][CPB2];
    stss[part][cpos] = tss;
    scs[part][cpos]  = cs;
    __syncthreads();

    __shared__ double s1[CPB2];
    __shared__ double s2[CPB2];
    if (tid < CPB2) {
        tss = 0.0; cs = 0.0;
        #pragma unroll
        for (int p = 0; p < PARTS; ++p) { tss += stss[p][tid]; cs += scs[p][tid]; }

        double t = 0.0, tc = 0.0;
        const int jj = blockIdx.x * CPB2 + tid;
        if (jj >= 1) {
            const double var = (double)variance[0];
            const double SQRT_2PI = 2.5066282746310005024;
            const double coef = 1.0 / (SQRT_2PI * var);
            const double score = coef * exp(-(tss * tss) / (2.0 * var * var));
            t  = tan(score);
            tc = t * cs;
        }
        s1[tid] = t; s2[tid] = tc;
    }
    __syncthreads();
    for (int s = CPB2 / 2; s > 0; s >>= 1) {
        if (tid < s) { s1[tid] += s1[tid + s]; s2[tid] += s2[tid + s]; }
        __syncthreads();
    }
    if (tid == 0) {
        blk[2 * blockIdx.x]     = s1[0];
        blk[2 * blockIdx.x + 1] = s2[0];
    }
}

// Stage 3: reduce F2BLK pairs in one wave (each lane takes 2 pairs).
__global__ __launch_bounds__(64) void tss_reduce_kernel(
    const double* __restrict__ blk,
    float* __restrict__ out)
{
    const int tid = threadIdx.x;
    double st  = blk[2 * tid]     + blk[2 * (tid + 64)];
    double stc = blk[2 * tid + 1] + blk[2 * (tid + 64) + 1];
    for (int o = 32; o > 0; o >>= 1) {
        st  += __shfl_down(st, o);
        stc += __shfl_down(stc, o);
    }
    if (tid == 0) out[0] = (float)(stc / st);
}

extern "C" void kernel_launch(void* const* d_in, const int* in_sizes, int n_in,
                              void* d_out, int out_size, void* d_ws, size_t ws_size,
                              hipStream_t stream) {
    const float* x   = (const float*)d_in[0];
    const float* var = (const float*)d_in[1];
    float* out = (float*)d_out;

    float* ptss = (float*)d_ws;                            // NCHUNK*NCOLS f32 (4 MiB)
    float* pcs  = ptss + (size_t)NCHUNK * NCOLS;           // NCHUNK*NCOLS f32 (4 MiB)
    double* blk = (double*)(pcs + (size_t)NCHUNK * NCOLS); // F2BLK*2 doubles

    tss_partial_kernel<<<NCHUNK, TPB, 0, stream>>>(x, ptss, pcs);
    tss_finalize_kernel<<<F2BLK, 256, 0, stream>>>(ptss, pcs, var, blk);
    tss_reduce_kernel<<<1, 64, 0, stream>>>(blk, out);
}